// Round 5
// baseline (1457.538 us; speedup 1.0000x reference)
//
#include <hip/hip_runtime.h>
#include <math.h>

// LSD (local shape descriptors), 128^3, 8 labels, sigma=5, truncate=3 -> 31-tap kernel.
//
// Algebra: for label mask m, define G_{abc} = (k_a *_z)(k_b *_y)(k_c *_x) m with
//   k0(u)=w(u), k1(u)=u w(u), k2(u)=u^2 w(u)  (w = normalized gaussian).
// At a voxel with mass=G000>0, p=G100/mass, q=G010/mass, s=G001/mass:
//   mean_offset = 0.5 - {p,q,s}/(2 sigma);  cov_ab = (G../mass - ..)/sigma^2.
// Translation-invariant: coords input not needed. Masks disjoint -> each voxel
// takes only its own label's descriptor.
//
// R1: XCD z-slab swizzle (7.25x pass_y overfetch fixed).
// R3: register-tiled sliding-window convs (VMEM-issue bound fixed), 794 us.
// R4: y+x fusion via LDS — but 48 KB tile -> 3 blocks/CU (Occupancy 10%) and
//     8-way LDS bank conflicts (1.97M, 8-lane runs at stride==0 mod 32 banks).
// R5: same fusion, resized: 8-row tile (4z x 2y), Bs[8][6][132] = 25.3 KB ->
//     6 blocks/CU (12 waves); +4-float row padding and 32-lane-contiguous
//     phase-2 mapping -> conflict-free b128 reads.

constexpr int NV = 128 * 128 * 128;
constexpr int SLICE = 128 * 128;
constexpr int R = 15;
constexpr int KL = 31;

struct Kw { float k0[KL]; float k1[KL]; float k2[KL]; };

__device__ __forceinline__ void fma4(float4& a, float w, const float4& b) {
    a.x = fmaf(w, b.x, a.x); a.y = fmaf(w, b.y, a.y);
    a.z = fmaf(w, b.z, a.z); a.w = fmaf(w, b.w, a.w);
}

__device__ __forceinline__ float4 load_mask4(const unsigned char* p, int lab) {
    unsigned int u = *(const unsigned int*)p;
    return make_float4(((u       ) & 255u) == (unsigned)lab ? 1.f : 0.f,
                       ((u >>  8 ) & 255u) == (unsigned)lab ? 1.f : 0.f,
                       ((u >> 16 ) & 255u) == (unsigned)lab ? 1.f : 0.f,
                       ((u >> 24 ) & 255u) == (unsigned)lab ? 1.f : 0.f);
}
__device__ __forceinline__ float4 load_mask4(const int* p, int lab) {
    int4 s = *(const int4*)p;
    return make_float4(s.x == lab ? 1.f : 0.f, s.y == lab ? 1.f : 0.f,
                       s.z == lab ? 1.f : 0.f, s.w == lab ? 1.f : 0.f);
}

__device__ __forceinline__ void seg_eq4(const unsigned char* p, int lab, bool m[4]) {
    unsigned int u = *(const unsigned int*)p;
    m[0] = ((u      ) & 255u) == (unsigned)lab;
    m[1] = ((u >>  8) & 255u) == (unsigned)lab;
    m[2] = ((u >> 16) & 255u) == (unsigned)lab;
    m[3] = ((u >> 24) & 255u) == (unsigned)lab;
}
__device__ __forceinline__ void seg_eq4(const int* p, int lab, bool m[4]) {
    int4 s = *(const int4*)p;
    m[0] = s.x == lab; m[1] = s.y == lab; m[2] = s.z == lab; m[3] = s.w == lab;
}

// ---------------- pass_z: seg -> A[3] (z-conv), tile: 4x (vec) x 4z --------
template <typename ST>
__global__ __launch_bounds__(256) void pass_z_t(const ST* __restrict__ seg,
                                                float* __restrict__ A,
                                                int label, Kw kw) {
    __shared__ float kp[3][37];           // zero-padded: kp[c][i] = k_c[i-3]
    if (threadIdx.x < 37) {
        int i = threadIdx.x, j = i - 3; bool ok = (j >= 0) && (j < KL);
        kp[0][i] = ok ? kw.k0[j] : 0.f;
        kp[1][i] = ok ? kw.k1[j] : 0.f;
        kp[2][i] = ok ? kw.k2[j] : 0.f;
    }
    __syncthreads();
    const int h = blockIdx.x, g = h & 7, l = h >> 3;       // 512 blocks
    const int tx = threadIdx.x & 31, ty = threadIdx.x >> 5;
    const int x0 = tx * 4;
    const int z0 = 16 * g + 4 * (l & 3);                   // XCD g owns z [16g,16g+16)
    const int y  = (l >> 2) * 8 + ty;

    float4 acc[4][3];
#pragma unroll
    for (int t = 0; t < 4; ++t)
#pragma unroll
        for (int c = 0; c < 3; ++c) acc[t][c] = make_float4(0.f, 0.f, 0.f, 0.f);

    for (int j = 0; j < 34; ++j) {                         // window: 4 outs + 30
        int zz = z0 + j - R;                               // uniform per wave
        float4 m = make_float4(0.f, 0.f, 0.f, 0.f);
        if ((unsigned)zz < 128u)
            m = load_mask4(seg + (zz * SLICE + y * 128 + x0), label);
#pragma unroll
        for (int t = 0; t < 4; ++t) {
            int i = j - t + 3;                             // padded weight index
            fma4(acc[t][0], kp[0][i], m);
            fma4(acc[t][1], kp[1][i], m);
            fma4(acc[t][2], kp[2][i], m);
        }
    }
#pragma unroll
    for (int t = 0; t < 4; ++t) {
        int base = (z0 + t) * SLICE + y * 128 + x0;
#pragma unroll
        for (int c = 0; c < 3; ++c)
            *(float4*)(A + (size_t)c * NV + base) = acc[t][c];
    }
}

// ---- x-conv helper: window from an LDS row, exact tap bounds folded -------
template <int NO>
__device__ __forceinline__ void convx_lds(const float* __restrict__ Brow, int x0,
                                          const Kw& kw, float o0[4], float o1[4],
                                          float o2[4]) {
    float W[36];
#pragma unroll
    for (int i = 0; i < 9; ++i) {
        int off = x0 - 16 + 4 * i;
        float4 w = ((unsigned)off < 128u) ? *(const float4*)(Brow + off)
                                          : make_float4(0.f, 0.f, 0.f, 0.f);
        W[4 * i] = w.x; W[4 * i + 1] = w.y; W[4 * i + 2] = w.z; W[4 * i + 3] = w.w;
    }
#pragma unroll
    for (int t = 0; t < 4; ++t) {
#pragma unroll
        for (int j = 0; j < KL; ++j) {                     // u = t+j+1 in [1,34]
            float wv = W[t + j + 1];
            o0[t] = fmaf(kw.k0[j], wv, o0[t]);
            if (NO > 1) o1[t] = fmaf(kw.k1[j], wv, o1[t]);
            if (NO > 2) o2[t] = fmaf(kw.k2[j], wv, o2[t]);
        }
    }
}

// ---------------- pass_yx: A[3] -> out (y-conv -> LDS -> x-conv + epilogue)
// block = 128 thr, tile = 8 rows (4z x 2y). Phase 1: (tx 0..31, tz 0..3)
// slides 2 y-outputs in regs -> Bs[8][6][132] (25.3 KB, padded). Phase 2:
// thread (tx=quad, rw=tid>>5) does rows rw, rw+4 at quad tx: 32-lane
// contiguous b128 reads, conflict-free.
template <typename ST>
__global__ __launch_bounds__(128, 3) void pass_yx(const float* __restrict__ A,
                                                  const ST* __restrict__ seg,
                                                  float* __restrict__ out,
                                                  int label, Kw kw) {
    __shared__ float kp[3][37];
    __shared__ float Bs[8][6][132];                        // 25,344 B
    if (threadIdx.x < 37) {
        int i = threadIdx.x, j = i - 3; bool ok = (j >= 0) && (j < KL);
        kp[0][i] = ok ? kw.k0[j] : 0.f;
        kp[1][i] = ok ? kw.k1[j] : 0.f;
        kp[2][i] = ok ? kw.k2[j] : 0.f;
    }
    __syncthreads();

    const int h = blockIdx.x, g = h & 7, l = h >> 3;       // 2048 blocks
    const int tx = threadIdx.x & 31, tz = threadIdx.x >> 5; // tz 0..3
    const int x0 = tx * 4;
    const int z0 = 16 * g + 4 * (l & 3);                   // XCD g owns z slab
    const int y0 = (l >> 2) * 2;                           // 64 y-tiles
    const int zs = (z0 + tz) * SLICE;

    // ---- phase 1: y-conv, 2 outputs sliding in registers ----
    float4 acc[6][2];
#pragma unroll
    for (int c = 0; c < 6; ++c)
#pragma unroll
        for (int t = 0; t < 2; ++t) acc[c][t] = make_float4(0.f, 0.f, 0.f, 0.f);

    for (int j = 0; j < 32; ++j) {                         // window: 2 outs + 30
        int yy = y0 + j - R;                               // uniform per block
        float4 a0 = make_float4(0.f, 0.f, 0.f, 0.f), a1 = a0, a2 = a0;
        if ((unsigned)yy < 128u) {
            int base = zs + yy * 128 + x0;
            a0 = *(const float4*)(A + base);
            a1 = *(const float4*)(A + NV + base);
            a2 = *(const float4*)(A + 2 * NV + base);
        }
#pragma unroll
        for (int t = 0; t < 2; ++t) {
            int i = j - t + 3;
            float w0 = kp[0][i], w1 = kp[1][i], w2 = kp[2][i];
            fma4(acc[0][t], w0, a0);
            fma4(acc[1][t], w1, a0);
            fma4(acc[2][t], w2, a0);
            fma4(acc[3][t], w0, a1);
            fma4(acc[4][t], w1, a1);
            fma4(acc[5][t], w0, a2);
        }
    }
#pragma unroll
    for (int t = 0; t < 2; ++t)
#pragma unroll
        for (int c = 0; c < 6; ++c)
            *(float4*)(&Bs[tz * 2 + t][c][x0]) = acc[c][t];

    __syncthreads();

    // ---- phase 2: x-conv + epilogue; thread -> quad tx of rows rw, rw+4 ---
    const int rw = threadIdx.x >> 5;                       // 0..3

#pragma unroll 1
    for (int rpass = 0; rpass < 2; ++rpass) {
        const int r = rw + 4 * rpass;                      // row 0..7
        const int z2 = z0 + (r >> 1);
        const int y2 = y0 + (r & 1);
        const int vrow = (z2 * 128 + y2) * 128;

        float g000[4] = {0,0,0,0}, g001[4] = {0,0,0,0}, g002[4] = {0,0,0,0},
              g010[4] = {0,0,0,0}, g011[4] = {0,0,0,0}, g020[4] = {0,0,0,0},
              g100[4] = {0,0,0,0}, g101[4] = {0,0,0,0}, g110[4] = {0,0,0,0},
              g200[4] = {0,0,0,0};

        convx_lds<3>(&Bs[r][0][0], x0, kw, g000, g001, g002);
        convx_lds<2>(&Bs[r][1][0], x0, kw, g010, g011, g011);
        convx_lds<1>(&Bs[r][2][0], x0, kw, g020, g020, g020);
        convx_lds<2>(&Bs[r][3][0], x0, kw, g100, g101, g101);
        convx_lds<1>(&Bs[r][4][0], x0, kw, g110, g110, g110);
        convx_lds<1>(&Bs[r][5][0], x0, kw, g200, g200, g200);

        bool msk[4];
        seg_eq4(seg + vrow + x0, label, msk);
#pragma unroll
        for (int t = 0; t < 4; ++t) {
            if (msk[t]) {
                int v = vrow + x0 + t;
                float mass = g000[t];
                float denom = (mass > 0.f) ? mass : 1.f;
                float inv = 1.f / denom;
                float p = g100[t] * inv, q = g010[t] * inv, s = g001[t] * inv;
                const float cs = 1.0f / 25.0f;             // 1/sigma^2
                float o[10];
                o[0] = 0.5f - 0.1f * p;                    // 1/(2 sigma) = 0.1
                o[1] = 0.5f - 0.1f * q;
                o[2] = 0.5f - 0.1f * s;
                o[3] = (g200[t] * inv - p * p) * cs;
                o[4] = (g020[t] * inv - q * q) * cs;
                o[5] = (g002[t] * inv - s * s) * cs;
                o[6] = (g110[t] * inv - p * q) * cs;
                o[7] = (g011[t] * inv - q * s) * cs;
                o[8] = (g101[t] * inv - p * s) * cs;
                o[9] = mass;
#pragma unroll
                for (int c = 0; c < 10; ++c) {
                    float val = fminf(fmaxf(o[c], 0.f), 1.f);
                    out[(size_t)c * NV + v] = val;
                }
            }
        }
    }
}

__global__ __launch_bounds__(256) void seg_to_u8(const int* __restrict__ seg,
                                                 unsigned char* __restrict__ seg8) {
    const int t = blockIdx.x * 256 + threadIdx.x;          // 2048 blocks
    const int4 s = ((const int4*)seg)[t];
    ((uchar4*)seg8)[t] = make_uchar4((unsigned char)s.x, (unsigned char)s.y,
                                     (unsigned char)s.z, (unsigned char)s.w);
}

extern "C" void kernel_launch(void* const* d_in, const int* in_sizes, int n_in,
                              void* d_out, int out_size, void* d_ws, size_t ws_size,
                              hipStream_t stream) {
    const int* seg = (const int*)d_in[0];
    // d_in[1] (coords) unused: math is translation-invariant.
    float* out = (float*)d_out;
    float* A = (float*)d_ws;                               // 3 volumes (24 MB)
    unsigned char* seg8 = (unsigned char*)(A + (size_t)3 * NV);
    const bool use8 = ws_size >= (size_t)3 * NV * sizeof(float) + NV;

    Kw kw;
    double gg[KL], S = 0.0;
    for (int j = 0; j < KL; ++j) { double d = j - R; gg[j] = exp(-0.5 * d * d / 25.0); S += gg[j]; }
    for (int j = 0; j < KL; ++j) {
        double gn = gg[j] / S, d = j - R;
        kw.k0[j] = (float)gn;
        kw.k1[j] = (float)(-d * gn);   // conv kernel k1 evaluated at (Z - t) = -d
        kw.k2[j] = (float)(d * d * gn);
    }

    hipMemsetAsync(d_out, 0, (size_t)out_size * sizeof(float), stream);

    if (use8) seg_to_u8<<<dim3(2048), dim3(256), 0, stream>>>(seg, seg8);
    for (int label = 1; label <= 8; ++label) {
        if (use8) {
            pass_z_t<unsigned char><<<dim3(512), dim3(256), 0, stream>>>(seg8, A, label, kw);
            pass_yx<unsigned char><<<dim3(2048), dim3(128), 0, stream>>>(A, seg8, out, label, kw);
        } else {
            pass_z_t<int><<<dim3(512), dim3(256), 0, stream>>>(seg, A, label, kw);
            pass_yx<int><<<dim3(2048), dim3(128), 0, stream>>>(A, seg, out, label, kw);
        }
    }
}

// Round 6
// 1381.961 us; speedup vs baseline: 1.0547x; 1.0547x over previous
//
#include <hip/hip_runtime.h>
#include <math.h>

// LSD (local shape descriptors), 128^3, 8 labels, sigma=5, truncate=3 -> 31-tap kernel.
//
// Algebra: for label mask m, define G_{abc} = (k_a *_z)(k_b *_y)(k_c *_x) m with
//   k0(u)=w(u), k1(u)=u w(u), k2(u)=u^2 w(u)  (w = normalized gaussian).
// At a voxel with mass=G000>0, p=G100/mass, q=G010/mass, s=G001/mass:
//   mean_offset = 0.5 - {p,q,s}/(2 sigma);  cov_ab = (G../mass - ..)/sigma^2.
// Translation-invariant: coords input not needed. Masks disjoint -> each voxel
// takes only its own label's descriptor.
//
// R1: XCD z-slab swizzle (7.25x pass_y overfetch fixed).
// R3: register-tiled sliding-window convs, separate passes: 794 us.
// R4: y+x fusion, 16-row/48KB tile, 128 thr: pass_yx 78 us but occ 10%
//     (3 blk/CU x 2 waves) and LDS conflicts.
// R5: FAILED: 8-row tile + 6 blk/CU doubled A-redundancy AND live working set
//     -> L2 thrash spiral (FETCH 16->217 MB, WRITE 59->232 MB via partial
//     dirty-line eviction/RFO). Lesson: keep live blocks/XCD and T-reuse at
//     R4 levels; the L2 cliff is sharp.
// R6: R4 geometry (1024 blocks, 16-row tile, 3 blk/CU) with 256 thr/block
//     (12 waves/CU): phase 1 = 8 slots x T=2 sliding y-outputs; phase 2 =
//     16 rows x 16 q-slots x 2; padded Bs rows (132) conflict-free.

constexpr int NV = 128 * 128 * 128;
constexpr int SLICE = 128 * 128;
constexpr int R = 15;
constexpr int KL = 31;

struct Kw { float k0[KL]; float k1[KL]; float k2[KL]; };

__device__ __forceinline__ void fma4(float4& a, float w, const float4& b) {
    a.x = fmaf(w, b.x, a.x); a.y = fmaf(w, b.y, a.y);
    a.z = fmaf(w, b.z, a.z); a.w = fmaf(w, b.w, a.w);
}

__device__ __forceinline__ float4 load_mask4(const unsigned char* p, int lab) {
    unsigned int u = *(const unsigned int*)p;
    return make_float4(((u       ) & 255u) == (unsigned)lab ? 1.f : 0.f,
                       ((u >>  8 ) & 255u) == (unsigned)lab ? 1.f : 0.f,
                       ((u >> 16 ) & 255u) == (unsigned)lab ? 1.f : 0.f,
                       ((u >> 24 ) & 255u) == (unsigned)lab ? 1.f : 0.f);
}
__device__ __forceinline__ float4 load_mask4(const int* p, int lab) {
    int4 s = *(const int4*)p;
    return make_float4(s.x == lab ? 1.f : 0.f, s.y == lab ? 1.f : 0.f,
                       s.z == lab ? 1.f : 0.f, s.w == lab ? 1.f : 0.f);
}

__device__ __forceinline__ void seg_eq4(const unsigned char* p, int lab, bool m[4]) {
    unsigned int u = *(const unsigned int*)p;
    m[0] = ((u      ) & 255u) == (unsigned)lab;
    m[1] = ((u >>  8) & 255u) == (unsigned)lab;
    m[2] = ((u >> 16) & 255u) == (unsigned)lab;
    m[3] = ((u >> 24) & 255u) == (unsigned)lab;
}
__device__ __forceinline__ void seg_eq4(const int* p, int lab, bool m[4]) {
    int4 s = *(const int4*)p;
    m[0] = s.x == lab; m[1] = s.y == lab; m[2] = s.z == lab; m[3] = s.w == lab;
}

// ---------------- pass_z: seg -> A[3] (z-conv), tile: 4x (vec) x 4z --------
template <typename ST>
__global__ __launch_bounds__(256) void pass_z_t(const ST* __restrict__ seg,
                                                float* __restrict__ A,
                                                int label, Kw kw) {
    __shared__ float kp[3][37];           // zero-padded: kp[c][i] = k_c[i-3]
    if (threadIdx.x < 37) {
        int i = threadIdx.x, j = i - 3; bool ok = (j >= 0) && (j < KL);
        kp[0][i] = ok ? kw.k0[j] : 0.f;
        kp[1][i] = ok ? kw.k1[j] : 0.f;
        kp[2][i] = ok ? kw.k2[j] : 0.f;
    }
    __syncthreads();
    const int h = blockIdx.x, g = h & 7, l = h >> 3;       // 512 blocks
    const int tx = threadIdx.x & 31, ty = threadIdx.x >> 5;
    const int x0 = tx * 4;
    const int z0 = 16 * g + 4 * (l & 3);                   // XCD g owns z [16g,16g+16)
    const int y  = (l >> 2) * 8 + ty;

    float4 acc[4][3];
#pragma unroll
    for (int t = 0; t < 4; ++t)
#pragma unroll
        for (int c = 0; c < 3; ++c) acc[t][c] = make_float4(0.f, 0.f, 0.f, 0.f);

    for (int j = 0; j < 34; ++j) {                         // window: 4 outs + 30
        int zz = z0 + j - R;                               // uniform per wave
        float4 m = make_float4(0.f, 0.f, 0.f, 0.f);
        if ((unsigned)zz < 128u)
            m = load_mask4(seg + (zz * SLICE + y * 128 + x0), label);
#pragma unroll
        for (int t = 0; t < 4; ++t) {
            int i = j - t + 3;                             // padded weight index
            fma4(acc[t][0], kp[0][i], m);
            fma4(acc[t][1], kp[1][i], m);
            fma4(acc[t][2], kp[2][i], m);
        }
    }
#pragma unroll
    for (int t = 0; t < 4; ++t) {
        int base = (z0 + t) * SLICE + y * 128 + x0;
#pragma unroll
        for (int c = 0; c < 3; ++c)
            *(float4*)(A + (size_t)c * NV + base) = acc[t][c];
    }
}

// ---- x-conv helper: window from an LDS row, exact tap bounds folded -------
template <int NO>
__device__ __forceinline__ void convx_lds(const float* __restrict__ Brow, int x0,
                                          const Kw& kw, float o0[4], float o1[4],
                                          float o2[4]) {
    float W[36];
#pragma unroll
    for (int i = 0; i < 9; ++i) {
        int off = x0 - 16 + 4 * i;
        float4 w = ((unsigned)off < 128u) ? *(const float4*)(Brow + off)
                                          : make_float4(0.f, 0.f, 0.f, 0.f);
        W[4 * i] = w.x; W[4 * i + 1] = w.y; W[4 * i + 2] = w.z; W[4 * i + 3] = w.w;
    }
#pragma unroll
    for (int t = 0; t < 4; ++t) {
#pragma unroll
        for (int j = 0; j < KL; ++j) {                     // u = t+j+1 in [1,34]
            float wv = W[t + j + 1];
            o0[t] = fmaf(kw.k0[j], wv, o0[t]);
            if (NO > 1) o1[t] = fmaf(kw.k1[j], wv, o1[t]);
            if (NO > 2) o2[t] = fmaf(kw.k2[j], wv, o2[t]);
        }
    }
}

// ---------------- pass_yx: A[3] -> out (y-conv -> LDS -> x-conv + epilogue)
// block = 256 thr, tile = 16 rows (4z x 4y), grid 1024 (R4 geometry: 3 blk/CU,
// 96 live blocks/XCD — stays under the L2 cliff). Phase 1: slot s=tid>>5
// (zsub=s&3, yp=s>>2) slides T=2 y-outputs. Phase 2: thread (rr=tid>>4,
// q=tid&15) does row rr at quads q, q+16: 32-lane-contiguous, padded rows.
template <typename ST>
__global__ __launch_bounds__(256, 3) void pass_yx(const float* __restrict__ A,
                                                  const ST* __restrict__ seg,
                                                  float* __restrict__ out,
                                                  int label, Kw kw) {
    __shared__ float kp[3][37];
    __shared__ __align__(16) float Bs[16][6][132];         // 50,688 B -> 3 blk/CU
    if (threadIdx.x < 37) {
        int i = threadIdx.x, j = i - 3; bool ok = (j >= 0) && (j < KL);
        kp[0][i] = ok ? kw.k0[j] : 0.f;
        kp[1][i] = ok ? kw.k1[j] : 0.f;
        kp[2][i] = ok ? kw.k2[j] : 0.f;
    }
    __syncthreads();

    const int h = blockIdx.x, g = h & 7, l = h >> 3;       // 1024 blocks
    const int z0 = 16 * g + 4 * (l & 3);                   // XCD g owns z slab
    const int y0 = (l >> 2) * 4;                           // 32 y-tiles

    // ---- phase 1: y-conv, 8 slots x T=2 outputs sliding in registers ----
    const int tx = threadIdx.x & 31, s = threadIdx.x >> 5; // s 0..7
    const int zsub = s & 3, yp = s >> 2;                   // yp 0..1
    const int x0 = tx * 4;
    const int zs = (z0 + zsub) * SLICE;
    const int ybase = y0 + 2 * yp;

    float4 acc[6][2];
#pragma unroll
    for (int c = 0; c < 6; ++c)
#pragma unroll
        for (int t = 0; t < 2; ++t) acc[c][t] = make_float4(0.f, 0.f, 0.f, 0.f);

    for (int j = 0; j < 32; ++j) {                         // window: 2 outs + 30
        int yy = ybase + j - R;
        float4 a0 = make_float4(0.f, 0.f, 0.f, 0.f), a1 = a0, a2 = a0;
        if ((unsigned)yy < 128u) {
            int base = zs + yy * 128 + x0;
            a0 = *(const float4*)(A + base);
            a1 = *(const float4*)(A + NV + base);
            a2 = *(const float4*)(A + 2 * NV + base);
        }
#pragma unroll
        for (int t = 0; t < 2; ++t) {
            int i = j - t + 3;
            float w0 = kp[0][i], w1 = kp[1][i], w2 = kp[2][i];
            fma4(acc[0][t], w0, a0);
            fma4(acc[1][t], w1, a0);
            fma4(acc[2][t], w2, a0);
            fma4(acc[3][t], w0, a1);
            fma4(acc[4][t], w1, a1);
            fma4(acc[5][t], w0, a2);
        }
    }
#pragma unroll
    for (int t = 0; t < 2; ++t) {
        const int row = 4 * zsub + 2 * yp + t;             // z-major row index
#pragma unroll
        for (int c = 0; c < 6; ++c)
            *(float4*)(&Bs[row][c][x0]) = acc[c][t];
    }

    __syncthreads();

    // ---- phase 2: x-conv + epilogue; thread -> row rr, quads q, q+16 ----
    const int q = threadIdx.x & 15, rr = threadIdx.x >> 4; // rr 0..15
    const int z2 = z0 + (rr >> 2);
    const int y2 = y0 + (rr & 3);
    const int vrow = (z2 * 128 + y2) * 128;

#pragma unroll 1
    for (int k = 0; k < 2; ++k) {
        const int xb = 4 * q + 64 * k;
        float g000[4] = {0,0,0,0}, g001[4] = {0,0,0,0}, g002[4] = {0,0,0,0},
              g010[4] = {0,0,0,0}, g011[4] = {0,0,0,0}, g020[4] = {0,0,0,0},
              g100[4] = {0,0,0,0}, g101[4] = {0,0,0,0}, g110[4] = {0,0,0,0},
              g200[4] = {0,0,0,0};

        convx_lds<3>(&Bs[rr][0][0], xb, kw, g000, g001, g002);
        convx_lds<2>(&Bs[rr][1][0], xb, kw, g010, g011, g011);
        convx_lds<1>(&Bs[rr][2][0], xb, kw, g020, g020, g020);
        convx_lds<2>(&Bs[rr][3][0], xb, kw, g100, g101, g101);
        convx_lds<1>(&Bs[rr][4][0], xb, kw, g110, g110, g110);
        convx_lds<1>(&Bs[rr][5][0], xb, kw, g200, g200, g200);

        bool msk[4];
        seg_eq4(seg + vrow + xb, label, msk);
#pragma unroll
        for (int t = 0; t < 4; ++t) {
            if (msk[t]) {
                int v = vrow + xb + t;
                float mass = g000[t];
                float denom = (mass > 0.f) ? mass : 1.f;
                float inv = 1.f / denom;
                float p = g100[t] * inv, q2 = g010[t] * inv, s2 = g001[t] * inv;
                const float cs = 1.0f / 25.0f;             // 1/sigma^2
                float o[10];
                o[0] = 0.5f - 0.1f * p;                    // 1/(2 sigma) = 0.1
                o[1] = 0.5f - 0.1f * q2;
                o[2] = 0.5f - 0.1f * s2;
                o[3] = (g200[t] * inv - p * p) * cs;
                o[4] = (g020[t] * inv - q2 * q2) * cs;
                o[5] = (g002[t] * inv - s2 * s2) * cs;
                o[6] = (g110[t] * inv - p * q2) * cs;
                o[7] = (g011[t] * inv - q2 * s2) * cs;
                o[8] = (g101[t] * inv - p * s2) * cs;
                o[9] = mass;
#pragma unroll
                for (int c = 0; c < 10; ++c) {
                    float val = fminf(fmaxf(o[c], 0.f), 1.f);
                    out[(size_t)c * NV + v] = val;
                }
            }
        }
    }
}

__global__ __launch_bounds__(256) void seg_to_u8(const int* __restrict__ seg,
                                                 unsigned char* __restrict__ seg8) {
    const int t = blockIdx.x * 256 + threadIdx.x;          // 2048 blocks
    const int4 s = ((const int4*)seg)[t];
    ((uchar4*)seg8)[t] = make_uchar4((unsigned char)s.x, (unsigned char)s.y,
                                     (unsigned char)s.z, (unsigned char)s.w);
}

extern "C" void kernel_launch(void* const* d_in, const int* in_sizes, int n_in,
                              void* d_out, int out_size, void* d_ws, size_t ws_size,
                              hipStream_t stream) {
    const int* seg = (const int*)d_in[0];
    // d_in[1] (coords) unused: math is translation-invariant.
    float* out = (float*)d_out;
    float* A = (float*)d_ws;                               // 3 volumes (24 MB)
    unsigned char* seg8 = (unsigned char*)(A + (size_t)3 * NV);
    const bool use8 = ws_size >= (size_t)3 * NV * sizeof(float) + NV;

    Kw kw;
    double gg[KL], S = 0.0;
    for (int j = 0; j < KL; ++j) { double d = j - R; gg[j] = exp(-0.5 * d * d / 25.0); S += gg[j]; }
    for (int j = 0; j < KL; ++j) {
        double gn = gg[j] / S, d = j - R;
        kw.k0[j] = (float)gn;
        kw.k1[j] = (float)(-d * gn);   // conv kernel k1 evaluated at (Z - t) = -d
        kw.k2[j] = (float)(d * d * gn);
    }

    hipMemsetAsync(d_out, 0, (size_t)out_size * sizeof(float), stream);

    if (use8) seg_to_u8<<<dim3(2048), dim3(256), 0, stream>>>(seg, seg8);
    for (int label = 1; label <= 8; ++label) {
        if (use8) {
            pass_z_t<unsigned char><<<dim3(512), dim3(256), 0, stream>>>(seg8, A, label, kw);
            pass_yx<unsigned char><<<dim3(1024), dim3(256), 0, stream>>>(A, seg8, out, label, kw);
        } else {
            pass_z_t<int><<<dim3(512), dim3(256), 0, stream>>>(seg, A, label, kw);
            pass_yx<int><<<dim3(1024), dim3(256), 0, stream>>>(A, seg, out, label, kw);
        }
    }
}

// Round 7
// 675.867 us; speedup vs baseline: 2.1565x; 2.0447x over previous
//
#include <hip/hip_runtime.h>
#include <math.h>

// LSD (local shape descriptors), 128^3, 8 labels, sigma=5, truncate=3 -> 31-tap kernel.
//
// Algebra: for label mask m, define G_{abc} = (k_a *_z)(k_b *_y)(k_c *_x) m with
//   k0(u)=w(u), k1(u)=u w(u), k2(u)=u^2 w(u)  (w = normalized gaussian).
// At a voxel with mass=G000>0, p=G100/mass, q=G010/mass, s=G001/mass:
//   mean_offset = 0.5 - {p,q,s}/(2 sigma);  cov_ab = (G../mass - ..)/sigma^2.
// Translation-invariant: coords input not needed. Masks disjoint -> each voxel
// takes only its own label's descriptor.
//
// R1: XCD z-slab swizzle (7.25x pass_y overfetch fixed).
// R3: register-tiled sliding-window convs, separate passes: 794 us.
// R4: y+x fused, 1024 blk x 128 thr, 16-row tile, T=4: 78 us/label,
//     FETCH 16 MB (works!) but 8-way LDS conflicts + occupancy 10%.
// R5/R6 FAILED: any T=2 phase-1 variant (2x A-request volume + 2x tile
//     turnover) falls off the L2 reuse cliff: FETCH 16 -> ~220 MB. Lesson:
//     keep R4's T=4 / 128-thr / 1024-block geometry exactly.
// R7: R4 geometry + padded LDS rows (conflict fix, verified in R5) +
//     label dim batched into blockIdx.y -> 4 total dispatches (was 26).
//     ~270 us of R3's time was inter-dispatch gap/tail. ws holds per-label
//     A: 8 labels x 3 vols x 8 MB = 201 MB (+2 MB seg8) < ~320 MB ws.

constexpr int NV = 128 * 128 * 128;
constexpr int SLICE = 128 * 128;
constexpr int R = 15;
constexpr int KL = 31;

struct Kw { float k0[KL]; float k1[KL]; float k2[KL]; };

__device__ __forceinline__ void fma4(float4& a, float w, const float4& b) {
    a.x = fmaf(w, b.x, a.x); a.y = fmaf(w, b.y, a.y);
    a.z = fmaf(w, b.z, a.z); a.w = fmaf(w, b.w, a.w);
}

__device__ __forceinline__ float4 load_mask4(const unsigned char* p, int lab) {
    unsigned int u = *(const unsigned int*)p;
    return make_float4(((u       ) & 255u) == (unsigned)lab ? 1.f : 0.f,
                       ((u >>  8 ) & 255u) == (unsigned)lab ? 1.f : 0.f,
                       ((u >> 16 ) & 255u) == (unsigned)lab ? 1.f : 0.f,
                       ((u >> 24 ) & 255u) == (unsigned)lab ? 1.f : 0.f);
}
__device__ __forceinline__ float4 load_mask4(const int* p, int lab) {
    int4 s = *(const int4*)p;
    return make_float4(s.x == lab ? 1.f : 0.f, s.y == lab ? 1.f : 0.f,
                       s.z == lab ? 1.f : 0.f, s.w == lab ? 1.f : 0.f);
}

__device__ __forceinline__ void seg_eq4(const unsigned char* p, int lab, bool m[4]) {
    unsigned int u = *(const unsigned int*)p;
    m[0] = ((u      ) & 255u) == (unsigned)lab;
    m[1] = ((u >>  8) & 255u) == (unsigned)lab;
    m[2] = ((u >> 16) & 255u) == (unsigned)lab;
    m[3] = ((u >> 24) & 255u) == (unsigned)lab;
}
__device__ __forceinline__ void seg_eq4(const int* p, int lab, bool m[4]) {
    int4 s = *(const int4*)p;
    m[0] = s.x == lab; m[1] = s.y == lab; m[2] = s.z == lab; m[3] = s.w == lab;
}

// -------- pass_z: seg -> A[lab][3] (z-conv). grid (512, nlab), 256 thr. ----
// label = label0 + blockIdx.y; A base offset = blockIdx.y * a_stride.
template <typename ST>
__global__ __launch_bounds__(256) void pass_z_t(const ST* __restrict__ seg,
                                                float* __restrict__ A,
                                                int label0, size_t a_stride,
                                                Kw kw) {
    __shared__ float kp[3][37];           // zero-padded: kp[c][i] = k_c[i-3]
    if (threadIdx.x < 37) {
        int i = threadIdx.x, j = i - 3; bool ok = (j >= 0) && (j < KL);
        kp[0][i] = ok ? kw.k0[j] : 0.f;
        kp[1][i] = ok ? kw.k1[j] : 0.f;
        kp[2][i] = ok ? kw.k2[j] : 0.f;
    }
    __syncthreads();
    const int label = label0 + blockIdx.y;
    float* Ab = A + (size_t)blockIdx.y * a_stride;
    const int h = blockIdx.x, g = h & 7, l = h >> 3;       // 512 x-blocks
    const int tx = threadIdx.x & 31, ty = threadIdx.x >> 5;
    const int x0 = tx * 4;
    const int z0 = 16 * g + 4 * (l & 3);                   // XCD g owns z [16g,16g+16)
    const int y  = (l >> 2) * 8 + ty;

    float4 acc[4][3];
#pragma unroll
    for (int t = 0; t < 4; ++t)
#pragma unroll
        for (int c = 0; c < 3; ++c) acc[t][c] = make_float4(0.f, 0.f, 0.f, 0.f);

    for (int j = 0; j < 34; ++j) {                         // window: 4 outs + 30
        int zz = z0 + j - R;                               // uniform per wave
        float4 m = make_float4(0.f, 0.f, 0.f, 0.f);
        if ((unsigned)zz < 128u)
            m = load_mask4(seg + (zz * SLICE + y * 128 + x0), label);
#pragma unroll
        for (int t = 0; t < 4; ++t) {
            int i = j - t + 3;                             // padded weight index
            fma4(acc[t][0], kp[0][i], m);
            fma4(acc[t][1], kp[1][i], m);
            fma4(acc[t][2], kp[2][i], m);
        }
    }
#pragma unroll
    for (int t = 0; t < 4; ++t) {
        int base = (z0 + t) * SLICE + y * 128 + x0;
#pragma unroll
        for (int c = 0; c < 3; ++c)
            *(float4*)(Ab + (size_t)c * NV + base) = acc[t][c];
    }
}

// ---- x-conv helper: window from an LDS row, exact tap bounds folded -------
template <int NO>
__device__ __forceinline__ void convx_lds(const float* __restrict__ Brow, int x0,
                                          const Kw& kw, float o0[4], float o1[4],
                                          float o2[4]) {
    float W[36];
#pragma unroll
    for (int i = 0; i < 9; ++i) {
        int off = x0 - 16 + 4 * i;
        float4 w = ((unsigned)off < 128u) ? *(const float4*)(Brow + off)
                                          : make_float4(0.f, 0.f, 0.f, 0.f);
        W[4 * i] = w.x; W[4 * i + 1] = w.y; W[4 * i + 2] = w.z; W[4 * i + 3] = w.w;
    }
#pragma unroll
    for (int t = 0; t < 4; ++t) {
#pragma unroll
        for (int j = 0; j < KL; ++j) {                     // u = t+j+1 in [1,34]
            float wv = W[t + j + 1];
            o0[t] = fmaf(kw.k0[j], wv, o0[t]);
            if (NO > 1) o1[t] = fmaf(kw.k1[j], wv, o1[t]);
            if (NO > 2) o2[t] = fmaf(kw.k2[j], wv, o2[t]);
        }
    }
}

// -------- pass_yx: A[lab][3] -> out. grid (1024, nlab), 128 thr. -----------
// R4 geometry: 16-row tile (4z x 4y), phase-1 T=4 sliding y-outputs; Bs rows
// padded to 132 floats (row stride 792 words = 24 mod 32 banks -> <=2-way,
// free). Phase 2: rr=tid>>3 rows, q0=tid&7, 4 k-iters.
template <typename ST>
__global__ __launch_bounds__(128) void pass_yx(const float* __restrict__ A,
                                               const ST* __restrict__ seg,
                                               float* __restrict__ out,
                                               int label0, size_t a_stride,
                                               Kw kw) {
    __shared__ float kp[3][37];
    __shared__ __align__(16) float Bs[16][6][132];         // 50,688 B -> 3 blk/CU
    if (threadIdx.x < 37) {
        int i = threadIdx.x, j = i - 3; bool ok = (j >= 0) && (j < KL);
        kp[0][i] = ok ? kw.k0[j] : 0.f;
        kp[1][i] = ok ? kw.k1[j] : 0.f;
        kp[2][i] = ok ? kw.k2[j] : 0.f;
    }
    __syncthreads();

    const int label = label0 + blockIdx.y;
    const float* Ab = A + (size_t)blockIdx.y * a_stride;
    const int h = blockIdx.x, g = h & 7, l = h >> 3;       // 1024 x-blocks
    const int tx = threadIdx.x & 31, tz = threadIdx.x >> 5; // tz 0..3
    const int x0 = tx * 4;
    const int z0 = 16 * g + 4 * (l & 3);                   // XCD g owns z slab
    const int y0 = (l >> 2) * 4;                           // 32 y-tiles
    const int zs = (z0 + tz) * SLICE;

    // ---- phase 1: y-conv, T=4 outputs sliding in registers ----
    float4 acc[6][4];                                      // [ch][t]
#pragma unroll
    for (int c = 0; c < 6; ++c)
#pragma unroll
        for (int t = 0; t < 4; ++t) acc[c][t] = make_float4(0.f, 0.f, 0.f, 0.f);

    for (int j = 0; j < 34; ++j) {                         // window: 4 outs + 30
        int yy = y0 + j - R;                               // uniform per block
        float4 a0 = make_float4(0.f, 0.f, 0.f, 0.f), a1 = a0, a2 = a0;
        if ((unsigned)yy < 128u) {
            int base = zs + yy * 128 + x0;
            a0 = *(const float4*)(Ab + base);
            a1 = *(const float4*)(Ab + NV + base);
            a2 = *(const float4*)(Ab + 2 * NV + base);
        }
#pragma unroll
        for (int t = 0; t < 4; ++t) {
            int i = j - t + 3;
            float w0 = kp[0][i], w1 = kp[1][i], w2 = kp[2][i];
            fma4(acc[0][t], w0, a0);
            fma4(acc[1][t], w1, a0);
            fma4(acc[2][t], w2, a0);
            fma4(acc[3][t], w0, a1);
            fma4(acc[4][t], w1, a1);
            fma4(acc[5][t], w0, a2);
        }
    }
#pragma unroll
    for (int t = 0; t < 4; ++t) {
        const int row = tz * 4 + t;                        // row = 4*zsub + ysub
#pragma unroll
        for (int c = 0; c < 6; ++c)
            *(float4*)(&Bs[row][c][x0]) = acc[c][t];
    }

    __syncthreads();

    // ---- phase 2: x-conv + epilogue; rr=tid>>3, quads q0+8k ----
    const int rr = threadIdx.x >> 3;                       // 0..15
    const int q0 = threadIdx.x & 7;
    const int z2 = z0 + (rr >> 2);
    const int y2 = y0 + (rr & 3);
    const int vrow = (z2 * 128 + y2) * 128;

#pragma unroll 1
    for (int k = 0; k < 4; ++k) {
        const int xb = 4 * (q0 + 8 * k);
        float g000[4] = {0,0,0,0}, g001[4] = {0,0,0,0}, g002[4] = {0,0,0,0},
              g010[4] = {0,0,0,0}, g011[4] = {0,0,0,0}, g020[4] = {0,0,0,0},
              g100[4] = {0,0,0,0}, g101[4] = {0,0,0,0}, g110[4] = {0,0,0,0},
              g200[4] = {0,0,0,0};

        convx_lds<3>(&Bs[rr][0][0], xb, kw, g000, g001, g002);
        convx_lds<2>(&Bs[rr][1][0], xb, kw, g010, g011, g011);
        convx_lds<1>(&Bs[rr][2][0], xb, kw, g020, g020, g020);
        convx_lds<2>(&Bs[rr][3][0], xb, kw, g100, g101, g101);
        convx_lds<1>(&Bs[rr][4][0], xb, kw, g110, g110, g110);
        convx_lds<1>(&Bs[rr][5][0], xb, kw, g200, g200, g200);

        bool msk[4];
        seg_eq4(seg + vrow + xb, label, msk);
#pragma unroll
        for (int t = 0; t < 4; ++t) {
            if (msk[t]) {
                int v = vrow + xb + t;
                float mass = g000[t];
                float denom = (mass > 0.f) ? mass : 1.f;
                float inv = 1.f / denom;
                float p = g100[t] * inv, q2 = g010[t] * inv, s2 = g001[t] * inv;
                const float cs = 1.0f / 25.0f;             // 1/sigma^2
                float o[10];
                o[0] = 0.5f - 0.1f * p;                    // 1/(2 sigma) = 0.1
                o[1] = 0.5f - 0.1f * q2;
                o[2] = 0.5f - 0.1f * s2;
                o[3] = (g200[t] * inv - p * p) * cs;
                o[4] = (g020[t] * inv - q2 * q2) * cs;
                o[5] = (g002[t] * inv - s2 * s2) * cs;
                o[6] = (g110[t] * inv - p * q2) * cs;
                o[7] = (g011[t] * inv - q2 * s2) * cs;
                o[8] = (g101[t] * inv - p * s2) * cs;
                o[9] = mass;
#pragma unroll
                for (int c = 0; c < 10; ++c) {
                    float val = fminf(fmaxf(o[c], 0.f), 1.f);
                    out[(size_t)c * NV + v] = val;
                }
            }
        }
    }
}

__global__ __launch_bounds__(256) void seg_to_u8(const int* __restrict__ seg,
                                                 unsigned char* __restrict__ seg8) {
    const int t = blockIdx.x * 256 + threadIdx.x;          // 2048 blocks
    const int4 s = ((const int4*)seg)[t];
    ((uchar4*)seg8)[t] = make_uchar4((unsigned char)s.x, (unsigned char)s.y,
                                     (unsigned char)s.z, (unsigned char)s.w);
}

extern "C" void kernel_launch(void* const* d_in, const int* in_sizes, int n_in,
                              void* d_out, int out_size, void* d_ws, size_t ws_size,
                              hipStream_t stream) {
    const int* seg = (const int*)d_in[0];
    // d_in[1] (coords) unused: math is translation-invariant.
    float* out = (float*)d_out;
    float* A = (float*)d_ws;
    const size_t AVOL = (size_t)3 * NV;                    // floats per label

    Kw kw;
    double gg[KL], S = 0.0;
    for (int j = 0; j < KL; ++j) { double d = j - R; gg[j] = exp(-0.5 * d * d / 25.0); S += gg[j]; }
    for (int j = 0; j < KL; ++j) {
        double gn = gg[j] / S, d = j - R;
        kw.k0[j] = (float)gn;
        kw.k1[j] = (float)(-d * gn);   // conv kernel k1 evaluated at (Z - t) = -d
        kw.k2[j] = (float)(d * d * gn);
    }

    hipMemsetAsync(d_out, 0, (size_t)out_size * sizeof(float), stream);

    const size_t need_all = 8 * AVOL * sizeof(float) + NV;  // A_all + seg8
    const size_t need_one = AVOL * sizeof(float) + NV;

    if (ws_size >= need_all) {
        // 4-dispatch path: label dim batched into blockIdx.y.
        unsigned char* seg8 = (unsigned char*)(A + 8 * AVOL);
        seg_to_u8<<<dim3(2048), dim3(256), 0, stream>>>(seg, seg8);
        pass_z_t<unsigned char><<<dim3(512, 8), dim3(256), 0, stream>>>(
            seg8, A, 1, AVOL, kw);
        pass_yx<unsigned char><<<dim3(1024, 8), dim3(128), 0, stream>>>(
            A, seg8, out, 1, AVOL, kw);
    } else if (ws_size >= need_one) {
        // per-label loop, shared A (R4-style with fixes)
        unsigned char* seg8 = (unsigned char*)(A + AVOL);
        seg_to_u8<<<dim3(2048), dim3(256), 0, stream>>>(seg, seg8);
        for (int label = 1; label <= 8; ++label) {
            pass_z_t<unsigned char><<<dim3(512, 1), dim3(256), 0, stream>>>(
                seg8, A, label, 0, kw);
            pass_yx<unsigned char><<<dim3(1024, 1), dim3(128), 0, stream>>>(
                A, seg8, out, label, 0, kw);
        }
    } else {
        // minimal path: int seg, shared A
        for (int label = 1; label <= 8; ++label) {
            pass_z_t<int><<<dim3(512, 1), dim3(256), 0, stream>>>(
                seg, A, label, 0, kw);
            pass_yx<int><<<dim3(1024, 1), dim3(128), 0, stream>>>(
                A, seg, out, label, 0, kw);
        }
    }
}

// Round 8
// 484.557 us; speedup vs baseline: 3.0080x; 1.3948x over previous
//
#include <hip/hip_runtime.h>
#include <hip/hip_bf16.h>
#include <math.h>

// LSD (local shape descriptors), 128^3, 8 labels, sigma=5, truncate=3 -> 31-tap kernel.
//
// Algebra: for label mask m, define G_{abc} = (k_a *_z)(k_b *_y)(k_c *_x) m with
//   k0(u)=w(u), k1(u)=u w(u), k2(u)=u^2 w(u)  (w = normalized gaussian).
// At a voxel with mass=G000>0, p=G100/mass, q=G010/mass, s=G001/mass:
//   mean_offset = 0.5 - {p,q,s}/(2 sigma);  cov_ab = (G../mass - ..)/sigma^2.
// Translation-invariant: coords input not needed. Masks disjoint -> each voxel
// takes only its own label's descriptor.
//
// R1: XCD z-slab swizzle (7.25x pass_y overfetch fixed).
// R3: register-tiled sliding-window convs, separate passes: 794 us.
// R4: y+x fused, 1024 blk x 128 thr, 16-row tile, T=4: FETCH 16 MB (works).
// R5/R6 FAILED: T=2 variants double A-request volume -> L2 reuse cliff
//     (FETCH 16 -> 220 MB). Lesson: keep T=4 / 128-thr / 1024-block geometry.
// R7: label batched into blockIdx.y, 4 dispatches total: 676 us; pass_yx
//     552 us, VALUBusy 48%, occupancy 16% -> issue/latency bound.
// R8: SPARSE phase 2. Only seg==label voxels (1/9 expected) need the final
//     x-conv: compact matches into an LDS list (atomicAdd), then per-lane
//     full 31-tap x 10-output conv only at matches (~8/9 of phase-2 FMA
//     deleted). B rows stored as bf16 with 16-elem zero pads -> reads are
//     unguarded ds_read_u16 at immediate offsets; LDS 51->33.5 KB ->
//     4 blk/CU. Dense fallback if >1024 matches (can't happen for the
//     benchmark's uniform seg, but correctness must not depend on input).

constexpr int NV = 128 * 128 * 128;
constexpr int SLICE = 128 * 128;
constexpr int R = 15;
constexpr int KL = 31;
constexpr int CSTRIDE = 160;            // u16: 16 pad + 128 data + 16 pad
constexpr int RSTRIDE = 6 * CSTRIDE + 8; // 968 u16; row stagger: 242w = 18 mod 32
constexpr int LCAP = 1024;

struct Kw { float k0[KL]; float k1[KL]; float k2[KL]; };

__device__ __forceinline__ void fma4(float4& a, float w, const float4& b) {
    a.x = fmaf(w, b.x, a.x); a.y = fmaf(w, b.y, a.y);
    a.z = fmaf(w, b.z, a.z); a.w = fmaf(w, b.w, a.w);
}

__device__ __forceinline__ float4 load_mask4(const unsigned char* p, int lab) {
    unsigned int u = *(const unsigned int*)p;
    return make_float4(((u       ) & 255u) == (unsigned)lab ? 1.f : 0.f,
                       ((u >>  8 ) & 255u) == (unsigned)lab ? 1.f : 0.f,
                       ((u >> 16 ) & 255u) == (unsigned)lab ? 1.f : 0.f,
                       ((u >> 24 ) & 255u) == (unsigned)lab ? 1.f : 0.f);
}
__device__ __forceinline__ float4 load_mask4(const int* p, int lab) {
    int4 s = *(const int4*)p;
    return make_float4(s.x == lab ? 1.f : 0.f, s.y == lab ? 1.f : 0.f,
                       s.z == lab ? 1.f : 0.f, s.w == lab ? 1.f : 0.f);
}

__device__ __forceinline__ void seg_eq4(const unsigned char* p, int lab, bool m[4]) {
    unsigned int u = *(const unsigned int*)p;
    m[0] = ((u      ) & 255u) == (unsigned)lab;
    m[1] = ((u >>  8) & 255u) == (unsigned)lab;
    m[2] = ((u >> 16) & 255u) == (unsigned)lab;
    m[3] = ((u >> 24) & 255u) == (unsigned)lab;
}
__device__ __forceinline__ void seg_eq4(const int* p, int lab, bool m[4]) {
    int4 s = *(const int4*)p;
    m[0] = s.x == lab; m[1] = s.y == lab; m[2] = s.z == lab; m[3] = s.w == lab;
}

__device__ __forceinline__ float bf_ld(const unsigned short* p) {
    return __uint_as_float(((unsigned int)(*p)) << 16);
}

// -------- pass_z: seg -> A[lab][3] (z-conv). grid (512, nlab), 256 thr. ----
template <typename ST>
__global__ __launch_bounds__(256) void pass_z_t(const ST* __restrict__ seg,
                                                float* __restrict__ A,
                                                int label0, size_t a_stride,
                                                Kw kw) {
    __shared__ float kp[3][37];           // zero-padded: kp[c][i] = k_c[i-3]
    if (threadIdx.x < 37) {
        int i = threadIdx.x, j = i - 3; bool ok = (j >= 0) && (j < KL);
        kp[0][i] = ok ? kw.k0[j] : 0.f;
        kp[1][i] = ok ? kw.k1[j] : 0.f;
        kp[2][i] = ok ? kw.k2[j] : 0.f;
    }
    __syncthreads();
    const int label = label0 + blockIdx.y;
    float* Ab = A + (size_t)blockIdx.y * a_stride;
    const int h = blockIdx.x, g = h & 7, l = h >> 3;       // 512 x-blocks
    const int tx = threadIdx.x & 31, ty = threadIdx.x >> 5;
    const int x0 = tx * 4;
    const int z0 = 16 * g + 4 * (l & 3);                   // XCD g owns z [16g,16g+16)
    const int y  = (l >> 2) * 8 + ty;

    float4 acc[4][3];
#pragma unroll
    for (int t = 0; t < 4; ++t)
#pragma unroll
        for (int c = 0; c < 3; ++c) acc[t][c] = make_float4(0.f, 0.f, 0.f, 0.f);

    for (int j = 0; j < 34; ++j) {                         // window: 4 outs + 30
        int zz = z0 + j - R;                               // uniform per wave
        float4 m = make_float4(0.f, 0.f, 0.f, 0.f);
        if ((unsigned)zz < 128u)
            m = load_mask4(seg + (zz * SLICE + y * 128 + x0), label);
#pragma unroll
        for (int t = 0; t < 4; ++t) {
            int i = j - t + 3;                             // padded weight index
            fma4(acc[t][0], kp[0][i], m);
            fma4(acc[t][1], kp[1][i], m);
            fma4(acc[t][2], kp[2][i], m);
        }
    }
#pragma unroll
    for (int t = 0; t < 4; ++t) {
        int base = (z0 + t) * SLICE + y * 128 + x0;
#pragma unroll
        for (int c = 0; c < 3; ++c)
            *(float4*)(Ab + (size_t)c * NV + base) = acc[t][c];
    }
}

// ---- per-voxel sparse x-conv + epilogue (B rows in bf16 LDS, zero-padded) -
__device__ __forceinline__ void do_voxel(const unsigned short* __restrict__ Bu,
                                         int rr, int x, int z0, int y0,
                                         float* __restrict__ out, const Kw& kw) {
    // value B(u) stored at row + c*CSTRIDE + 16 + u; window tap j reads
    // B(x-15+j) -> index x+1+j in [1,159) for x in [0,128). Pads are zero.
    const unsigned short* row = Bu + rr * RSTRIDE + (x + 1);
    float g000 = 0, g001 = 0, g002 = 0, g010 = 0, g011 = 0,
          g020 = 0, g100 = 0, g101 = 0, g110 = 0, g200 = 0;
#pragma unroll
    for (int j = 0; j < KL; ++j) {
        float w0 = kw.k0[j], w1 = kw.k1[j], w2 = kw.k2[j];
        float b0 = bf_ld(row + 0 * CSTRIDE + j);
        float b1 = bf_ld(row + 1 * CSTRIDE + j);
        float b2 = bf_ld(row + 2 * CSTRIDE + j);
        float b3 = bf_ld(row + 3 * CSTRIDE + j);
        float b4 = bf_ld(row + 4 * CSTRIDE + j);
        float b5 = bf_ld(row + 5 * CSTRIDE + j);
        g000 = fmaf(w0, b0, g000); g001 = fmaf(w1, b0, g001); g002 = fmaf(w2, b0, g002);
        g010 = fmaf(w0, b1, g010); g011 = fmaf(w1, b1, g011);
        g020 = fmaf(w0, b2, g020);
        g100 = fmaf(w0, b3, g100); g101 = fmaf(w1, b3, g101);
        g110 = fmaf(w0, b4, g110);
        g200 = fmaf(w0, b5, g200);
    }
    const int z2 = z0 + (rr >> 2), y2 = y0 + (rr & 3);
    const int v = (z2 * 128 + y2) * 128 + x;
    float mass = g000;
    float denom = (mass > 0.f) ? mass : 1.f;
    float inv = 1.f / denom;
    float p = g100 * inv, q = g010 * inv, s = g001 * inv;
    const float cs = 1.0f / 25.0f;                         // 1/sigma^2
    float o[10];
    o[0] = 0.5f - 0.1f * p;                                // 1/(2 sigma) = 0.1
    o[1] = 0.5f - 0.1f * q;
    o[2] = 0.5f - 0.1f * s;
    o[3] = (g200 * inv - p * p) * cs;
    o[4] = (g020 * inv - q * q) * cs;
    o[5] = (g002 * inv - s * s) * cs;
    o[6] = (g110 * inv - p * q) * cs;
    o[7] = (g011 * inv - q * s) * cs;
    o[8] = (g101 * inv - p * s) * cs;
    o[9] = mass;
#pragma unroll
    for (int c = 0; c < 10; ++c) {
        float val = fminf(fmaxf(o[c], 0.f), 1.f);
        out[(size_t)c * NV + v] = val;
    }
}

// -------- pass_yx: A[lab][3] -> out. grid (1024, nlab), 128 thr. -----------
// Phase 1 (R4 geometry): 16-row tile (4z x 4y), T=4 sliding y-outputs ->
// bf16 LDS rows with zero pads. Compaction: seg==label voxels -> LDS list.
// Phase 2: per-lane full conv at matched voxels only (expected 1/9 density).
template <typename ST>
__global__ __launch_bounds__(128) void pass_yx(const float* __restrict__ A,
                                               const ST* __restrict__ seg,
                                               float* __restrict__ out,
                                               int label0, size_t a_stride,
                                               Kw kw) {
    __shared__ float kp[3][37];
    __shared__ __align__(16) unsigned short Bu[16 * RSTRIDE]; // 30,976 B
    __shared__ unsigned short lst[LCAP];                      // 2 KB
    __shared__ int cnt;

    // zero Bs (pads must be exactly 0) + weights + counter
    {
        uint4 z4 = make_uint4(0, 0, 0, 0);
        uint4* b4 = (uint4*)Bu;                            // 16*968/8 = 1936
        for (int i = threadIdx.x; i < 1936; i += 128) b4[i] = z4;
    }
    if (threadIdx.x < 37) {
        int i = threadIdx.x, j = i - 3; bool ok = (j >= 0) && (j < KL);
        kp[0][i] = ok ? kw.k0[j] : 0.f;
        kp[1][i] = ok ? kw.k1[j] : 0.f;
        kp[2][i] = ok ? kw.k2[j] : 0.f;
    }
    if (threadIdx.x == 0) cnt = 0;
    __syncthreads();

    const int label = label0 + blockIdx.y;
    const float* Ab = A + (size_t)blockIdx.y * a_stride;
    const int h = blockIdx.x, g = h & 7, l = h >> 3;       // 1024 x-blocks
    const int tx = threadIdx.x & 31, tz = threadIdx.x >> 5; // tz 0..3
    const int x0 = tx * 4;
    const int z0 = 16 * g + 4 * (l & 3);                   // XCD g owns z slab
    const int y0 = (l >> 2) * 4;                           // 32 y-tiles
    const int zs = (z0 + tz) * SLICE;

    // ---- phase 1: y-conv, T=4 outputs sliding in registers ----
    float4 acc[6][4];                                      // [ch][t]
#pragma unroll
    for (int c = 0; c < 6; ++c)
#pragma unroll
        for (int t = 0; t < 4; ++t) acc[c][t] = make_float4(0.f, 0.f, 0.f, 0.f);

    for (int j = 0; j < 34; ++j) {                         // window: 4 outs + 30
        int yy = y0 + j - R;                               // uniform per block
        float4 a0 = make_float4(0.f, 0.f, 0.f, 0.f), a1 = a0, a2 = a0;
        if ((unsigned)yy < 128u) {
            int base = zs + yy * 128 + x0;
            a0 = *(const float4*)(Ab + base);
            a1 = *(const float4*)(Ab + NV + base);
            a2 = *(const float4*)(Ab + 2 * NV + base);
        }
#pragma unroll
        for (int t = 0; t < 4; ++t) {
            int i = j - t + 3;
            float w0 = kp[0][i], w1 = kp[1][i], w2 = kp[2][i];
            fma4(acc[0][t], w0, a0);
            fma4(acc[1][t], w1, a0);
            fma4(acc[2][t], w2, a0);
            fma4(acc[3][t], w0, a1);
            fma4(acc[4][t], w1, a1);
            fma4(acc[5][t], w0, a2);
        }
    }
#pragma unroll
    for (int t = 0; t < 4; ++t) {
        const int row = tz * 4 + t;                        // row = 4*zsub + ysub
#pragma unroll
        for (int c = 0; c < 6; ++c) {
            __hip_bfloat162 lo = __float22bfloat162_rn(make_float2(acc[c][t].x, acc[c][t].y));
            __hip_bfloat162 hi = __float22bfloat162_rn(make_float2(acc[c][t].z, acc[c][t].w));
            unsigned short* dst = Bu + row * RSTRIDE + c * CSTRIDE + 16 + x0;
            *reinterpret_cast<__hip_bfloat162*>(dst)     = lo;
            *reinterpret_cast<__hip_bfloat162*>(dst + 2) = hi;
        }
    }

    // ---- compaction: this tile's seg==label voxels -> lst ----
    {
        const int rr = threadIdx.x >> 3, q0 = threadIdx.x & 7;
        const int z2 = z0 + (rr >> 2), y2 = y0 + (rr & 3);
        const int vrow = (z2 * 128 + y2) * 128;
#pragma unroll
        for (int k = 0; k < 4; ++k) {
            const int xb = 4 * (q0 + 8 * k);
            bool m[4];
            seg_eq4(seg + vrow + xb, label, m);
#pragma unroll
            for (int t = 0; t < 4; ++t) {
                if (m[t]) {
                    int pos = atomicAdd(&cnt, 1);
                    if (pos < LCAP)
                        lst[pos] = (unsigned short)((rr << 7) | (xb + t));
                }
            }
        }
    }

    __syncthreads();

    // ---- phase 2: sparse x-conv + epilogue ----
    const int total = cnt;
    if (total <= LCAP) {
        for (int e = threadIdx.x; e < total; e += 128) {
            int ent = lst[e];
            do_voxel(Bu, ent >> 7, ent & 127, z0, y0, out, kw);
        }
    } else {
        // adversarial-density fallback: dense masked sweep (same math)
        for (int e = threadIdx.x; e < 2048; e += 128) {
            int rr = e >> 7, x = e & 127;
            int z2 = z0 + (rr >> 2), y2 = y0 + (rr & 3);
            if (seg[(z2 * 128 + y2) * 128 + x] == (ST)label)
                do_voxel(Bu, rr, x, z0, y0, out, kw);
        }
    }
}

__global__ __launch_bounds__(256) void seg_to_u8(const int* __restrict__ seg,
                                                 unsigned char* __restrict__ seg8) {
    const int t = blockIdx.x * 256 + threadIdx.x;          // 2048 blocks
    const int4 s = ((const int4*)seg)[t];
    ((uchar4*)seg8)[t] = make_uchar4((unsigned char)s.x, (unsigned char)s.y,
                                     (unsigned char)s.z, (unsigned char)s.w);
}

extern "C" void kernel_launch(void* const* d_in, const int* in_sizes, int n_in,
                              void* d_out, int out_size, void* d_ws, size_t ws_size,
                              hipStream_t stream) {
    const int* seg = (const int*)d_in[0];
    // d_in[1] (coords) unused: math is translation-invariant.
    float* out = (float*)d_out;
    float* A = (float*)d_ws;
    const size_t AVOL = (size_t)3 * NV;                    // floats per label

    Kw kw;
    double gg[KL], S = 0.0;
    for (int j = 0; j < KL; ++j) { double d = j - R; gg[j] = exp(-0.5 * d * d / 25.0); S += gg[j]; }
    for (int j = 0; j < KL; ++j) {
        double gn = gg[j] / S, d = j - R;
        kw.k0[j] = (float)gn;
        kw.k1[j] = (float)(-d * gn);   // conv kernel k1 evaluated at (Z - t) = -d
        kw.k2[j] = (float)(d * d * gn);
    }

    hipMemsetAsync(d_out, 0, (size_t)out_size * sizeof(float), stream);

    const size_t need_all = 8 * AVOL * sizeof(float) + NV;  // A_all + seg8
    const size_t need_one = AVOL * sizeof(float) + NV;

    if (ws_size >= need_all) {
        // 4-dispatch path: label dim batched into blockIdx.y.
        unsigned char* seg8 = (unsigned char*)(A + 8 * AVOL);
        seg_to_u8<<<dim3(2048), dim3(256), 0, stream>>>(seg, seg8);
        pass_z_t<unsigned char><<<dim3(512, 8), dim3(256), 0, stream>>>(
            seg8, A, 1, AVOL, kw);
        pass_yx<unsigned char><<<dim3(1024, 8), dim3(128), 0, stream>>>(
            A, seg8, out, 1, AVOL, kw);
    } else if (ws_size >= need_one) {
        unsigned char* seg8 = (unsigned char*)(A + AVOL);
        seg_to_u8<<<dim3(2048), dim3(256), 0, stream>>>(seg, seg8);
        for (int label = 1; label <= 8; ++label) {
            pass_z_t<unsigned char><<<dim3(512, 1), dim3(256), 0, stream>>>(
                seg8, A, label, 0, kw);
            pass_yx<unsigned char><<<dim3(1024, 1), dim3(128), 0, stream>>>(
                A, seg8, out, label, 0, kw);
        }
    } else {
        for (int label = 1; label <= 8; ++label) {
            pass_z_t<int><<<dim3(512, 1), dim3(256), 0, stream>>>(
                seg, A, label, 0, kw);
            pass_yx<int><<<dim3(1024, 1), dim3(128), 0, stream>>>(
                A, seg, out, label, 0, kw);
        }
    }
}